// Round 9
// baseline (1226.837 us; speedup 1.0000x reference)
//
#include <hip/hip_runtime.h>
#include <hip/hip_bf16.h>
#include <stdint.h>

#define TOKENS 4096
#define DDIM 1024
#define FDIM 4096
#define NEXP 8
#define BM 128
#define BN 128
#define BK2 32

typedef __attribute__((ext_vector_type(4))) float f32x4;
typedef __attribute__((ext_vector_type(8))) short short8;

__device__ __forceinline__ unsigned short f2bf(float f) {
    union { float f; uint32_t u; } v; v.f = f;
    uint32_t u = v.u;
    return (unsigned short)((u + 0x7fff + ((u >> 16) & 1)) >> 16);
}

#define BARRIER() asm volatile("s_barrier" ::: "memory")
#define WAIT_VM0() asm volatile("s_waitcnt vmcnt(0)" ::: "memory")
#define WAIT_VM4() asm volatile("s_waitcnt vmcnt(4)" ::: "memory")
#define WAIT_LGKM0() asm volatile("s_waitcnt lgkmcnt(0)" ::: "memory")
#define GLDS(SRC, DST) __builtin_amdgcn_global_load_lds( \
    (const __attribute__((address_space(1))) void*)(SRC), \
    (__attribute__((address_space(3))) void*)(DST), 16, 0, 0)

// opaque asm LDS read: explicit waits control all ordering (rule #18 applied at use)
__device__ __forceinline__ short8 dsr(uint32_t addr) {
    short8 d;
    asm volatile("ds_read_b128 %0, %1" : "=v"(d) : "v"(addr));
    return d;
}

// ---------------- X f32 -> bf16 ----------------
__global__ __launch_bounds__(256) void cvt_x(const float* __restrict__ x,
                                             unsigned short* __restrict__ xb, int n) {
    int i = (blockIdx.x * 256 + threadIdx.x) * 8;
    if (i >= n) return;
    float4 a = *(const float4*)(x + i);
    float4 b = *(const float4*)(x + i + 4);
    short8 o;
    o[0] = f2bf(a.x); o[1] = f2bf(a.y); o[2] = f2bf(a.z); o[3] = f2bf(a.w);
    o[4] = f2bf(b.x); o[5] = f2bf(b.y); o[6] = f2bf(b.z); o[7] = f2bf(b.w);
    *(short8*)(xb + i) = o;
}

// ------------- transpose + cvt: in [E][R][C] f32 -> out [E][C][R] bf16 -------------
__global__ __launch_bounds__(256) void transpose_cvt(const float* __restrict__ in,
                                                     unsigned short* __restrict__ out,
                                                     int R, int C) {
    __shared__ float tile[32][33];
    int e = blockIdx.z;
    int r0 = blockIdx.y * 32, c0 = blockIdx.x * 32;
    const float* src = in + (size_t)e * R * C;
    unsigned short* dst = out + (size_t)e * R * C;
    int t = threadIdx.x;
    int rr = t >> 3;
    int cc = (t & 7) * 4;
    float4 v = *(const float4*)(src + (size_t)(r0 + rr) * C + c0 + cc);
    tile[rr][cc + 0] = v.x; tile[rr][cc + 1] = v.y;
    tile[rr][cc + 2] = v.z; tile[rr][cc + 3] = v.w;
    __syncthreads();
    int oc = rr;
    int orr = cc;
    ushort4 o;
    o.x = f2bf(tile[orr + 0][oc]);
    o.y = f2bf(tile[orr + 1][oc]);
    o.z = f2bf(tile[orr + 2][oc]);
    o.w = f2bf(tile[orr + 3][oc]);
    *(ushort4*)(dst + (size_t)(c0 + oc) * R + r0 + orr) = o;
}

// ---------------- router: top-2 of 8 logits, build expert lists ----------------
__global__ __launch_bounds__(256) void router(const float* __restrict__ x,
                                              const float* __restrict__ wr,
                                              int* __restrict__ cnt,
                                              int* __restrict__ list) {
    __shared__ float wl[NEXP * DDIM];
    int t = threadIdx.x;
    for (int i = t; i < NEXP * DDIM; i += 256) wl[i] = wr[i];
    __syncthreads();
    int tok = blockIdx.x * 4 + (t >> 6);
    int lane = t & 63;
    float acc[NEXP];
#pragma unroll
    for (int e = 0; e < NEXP; e++) acc[e] = 0.f;
    const float* xr = x + (size_t)tok * DDIM;
    for (int d = lane; d < DDIM; d += 64) {
        float xv = xr[d];
#pragma unroll
        for (int e = 0; e < NEXP; e++) acc[e] += xv * wl[e * DDIM + d];
    }
#pragma unroll
    for (int e = 0; e < NEXP; e++) {
#pragma unroll
        for (int off = 32; off; off >>= 1) acc[e] += __shfl_xor(acc[e], off);
    }
    if (lane == 0) {
        int e1 = 0; float v1 = acc[0];
        for (int e = 1; e < NEXP; e++) if (acc[e] > v1) { v1 = acc[e]; e1 = e; }
        int e2 = -1; float v2 = -1e30f;
        for (int e = 0; e < NEXP; e++) if (e != e1 && acc[e] > v2) { v2 = acc[e]; e2 = e; }
        int p1 = atomicAdd(&cnt[e1], 1);
        list[e1 * TOKENS + p1] = tok;
        int p2 = atomicAdd(&cnt[e2], 1);
        list[e2 * TOKENS + p2] = tok;
    }
}

// ---------------- setup: offsets, work bases, per-XCD queue ranges ----------------
__global__ void setup(const int* __restrict__ cnt, int* __restrict__ off,
                      int* __restrict__ wbA, int* __restrict__ wbB,
                      int* __restrict__ qA, int* __restrict__ qlA,
                      int* __restrict__ qB, int* __restrict__ qlB) {
    if (threadIdx.x == 0) {
        int s = 0, ta = 0, tb = 0;
        for (int e = 0; e < NEXP; e++) {
            off[e] = s; s += cnt[e];
            wbA[e] = ta; wbB[e] = tb;
            int ntm = (cnt[e] + BM - 1) / BM;
            ta += ntm * (FDIM / BN);        // pass A: 32 n-tiles
            tb += ntm * (DDIM / BN) * 2;    // pass B: 8 n-tiles x 2 k-chunks
        }
        wbA[NEXP] = ta; wbB[NEXP] = tb;
        for (int x = 0; x < 8; x++) {
            qA[x]  = (int)((long)ta * x / 8);
            qlA[x] = (int)((long)ta * (x + 1) / 8);
            qB[x]  = (int)((long)tb * x / 8);
            qlB[x] = (int)((long)tb * (x + 1) / 8);
        }
    }
}

// ---------------- persistent grouped GEMM: 128^2, BK=32, 3-slot ring, 3 blk/CU ----------------
// Round-8 skeleton verbatim; only the work-pop changed: 8 per-XCD queues + stealing scan.
template <bool GATHER_A, bool SILU, int KSPLIT>
__global__ __launch_bounds__(256, 3) void gemm_moe9(
    const unsigned short* __restrict__ Abase,
    const unsigned short* __restrict__ Wt,      // [E][NW][KD] bf16
    const int* __restrict__ cnt, const int* __restrict__ off,
    const int* __restrict__ list,
    const int* __restrict__ wbase,
    int* __restrict__ qctr, const int* __restrict__ qlim,
    unsigned short* __restrict__ Hout,          // SILU out, stride NW
    float* __restrict__ Yout,                   // atomic out, stride NW
    int KD, int KLEN, int NW) {
    __shared__ alignas(16) unsigned short As[3][BM * BK2];  // 3 x 8 KB
    __shared__ alignas(16) unsigned short Bs[3][BN * BK2];  // 3 x 8 KB
    __shared__ int wsh;

    const int t = threadIdx.x;
    const int lane = t & 63;
    const int wid = t >> 6;
    const int wm = wid >> 1, wn = wid & 1;
    const int r16 = lane & 15, g = lane >> 4;

    // XCD id -> home queue (any value is correct; affects locality only)
    uint32_t xcd;
    asm volatile("s_getreg_b32 %0, hwreg(HW_REG_XCC_ID)" : "=s"(xcd));
    int myq = (int)(xcd & 7);

    // frag addresses within a slot (slot 0 base); chunk g stored at g^((row>>1)&3)
    const uint32_t asB = (uint32_t)(uintptr_t)&As[0][0];
    const uint32_t bsB = (uint32_t)(uintptr_t)&Bs[0][0];
    uint32_t aAdr[4], bAdr[4];
#pragma unroll
    for (int mi = 0; mi < 4; mi++) {
        int row = wm * 64 + mi * 16 + r16;
        aAdr[mi] = asB + row * 64 + ((g ^ ((row >> 1) & 3)) << 4);
    }
#pragma unroll
    for (int nj = 0; nj < 4; nj++) {
        int row = wn * 64 + nj * 16 + r16;
        bAdr[nj] = bsB + row * 64 + ((g ^ ((row >> 1) & 3)) << 4);
    }

    for (;;) {
        if (t == 0) {
            int w = -1;
            // scan own queue first, then steal; empty queues stay empty (monotonic)
            for (int k = 0; k < 8 && w < 0; k++) {
                int q = (myq + k) & 7;
                int cand = atomicAdd(&qctr[q], 1);
                if (cand < qlim[q]) { w = cand; myq = q; }
            }
            wsh = w;
        }
        __syncthreads();
        int w = wsh;
        if (w < 0) break;

        // ---- decode: expert e; (n-tile [, k-chunk]) outer, m-tile inner ----
        int e = 0;
        while (e < NEXP - 1 && w >= wbase[e + 1]) e++;
        w -= wbase[e];
        const int n_e = cnt[e];
        const int ntm = (n_e + BM - 1) >> 7;
        int idx = w / ntm;
        const int mtile = w - idx * ntm;
        int kc = 0;
        if (KSPLIT == 2) { kc = idx & 1; idx >>= 1; }
        const int m0 = mtile * BM;
        const int n0 = idx * BN;
        const int base = off[e];
        const int k0 = kc * KLEN;

        // ---- staging pointers: 2 A + 2 B chunks of 16 B per thread per tile ----
        const unsigned short* pA[2];
        const unsigned short* pB[2];
        int ldsOff[2];
#pragma unroll
        for (int i = 0; i < 2; i++) {
            int c = i * 256 + t;
            int row = c >> 2, p = c & 3;
            int cg = p ^ ((row >> 1) & 3);
            int arow = m0 + row; if (arow >= n_e) arow = n_e - 1;
            size_t grow = GATHER_A ? (size_t)list[e * TOKENS + arow] : (size_t)(base + arow);
            pA[i] = Abase + grow * (size_t)KD + k0 + (cg << 3);
            pB[i] = Wt + ((size_t)e * NW + n0 + row) * (size_t)KD + k0 + (cg << 3);
            ldsOff[i] = c * 16;
        }

        f32x4 acc[4][4];
#pragma unroll
        for (int i = 0; i < 4; i++)
#pragma unroll
            for (int j = 0; j < 4; j++) acc[i][j] = f32x4{0.f, 0.f, 0.f, 0.f};

        // ---- prologue: stage tiles 0,1 into slots 0,1 ----
#pragma unroll
        for (int s = 0; s < 2; ++s) {
#pragma unroll
            for (int i = 0; i < 2; i++) { GLDS(pA[i], (char*)As[s] + ldsOff[i]); pA[i] += BK2; }
#pragma unroll
            for (int i = 0; i < 2; i++) { GLDS(pB[i], (char*)Bs[s] + ldsOff[i]); pB[i] += BK2; }
        }
        WAIT_VM4();   // tile 0 resident; tile 1 still in flight
        BARRIER();

        // rotating ring-slot byte offsets: compute o0, ready o1, stage o2
        uint32_t o0 = 0, o1 = 8192, o2 = 16384;

        const int NT = KLEN / BK2;
        for (int tk = 0; tk < NT; ++tk) {
            // issue stage for tile tk+2 into the slot freed at last barrier
            if (tk + 2 < NT) {
#pragma unroll
                for (int i = 0; i < 2; i++) { GLDS(pA[i], (char*)As[0] + o2 + ldsOff[i]); pA[i] += BK2; }
#pragma unroll
                for (int i = 0; i < 2; i++) { GLDS(pB[i], (char*)Bs[0] + o2 + ldsOff[i]); pB[i] += BK2; }
            }

            // fragment loads: opaque asm ds_read_b128 from compute slot
            short8 a0 = dsr(aAdr[0] + o0);
            short8 a1 = dsr(aAdr[1] + o0);
            short8 a2 = dsr(aAdr[2] + o0);
            short8 a3 = dsr(aAdr[3] + o0);
            short8 b0 = dsr(bAdr[0] + o0);
            short8 b1 = dsr(bAdr[1] + o0);
            short8 b2 = dsr(bAdr[2] + o0);
            short8 b3 = dsr(bAdr[3] + o0);
            WAIT_LGKM0();
            __builtin_amdgcn_sched_barrier(0);   // rule #18

            __builtin_amdgcn_s_setprio(1);
            acc[0][0] = __builtin_amdgcn_mfma_f32_16x16x32_bf16(a0, b0, acc[0][0], 0, 0, 0);
            acc[0][1] = __builtin_amdgcn_mfma_f32_16x16x32_bf16(a0, b1, acc[0][1], 0, 0, 0);
            acc[0][2] = __builtin_amdgcn_mfma_f32_16x16x32_bf16(a0, b2, acc[0][2], 0, 0, 0);
            acc[0][3] = __builtin_amdgcn_mfma_f32_16x16x32_bf16(a0, b3, acc[0][3], 0, 0, 0);
            acc[1][0] = __builtin_amdgcn_mfma_f32_16x16x32_bf16(a1, b0, acc[1][0], 0, 0, 0);
            acc[1][1] = __builtin_amdgcn_mfma_f32_16x16x32_bf16(a1, b1, acc[1][1], 0, 0, 0);
            acc[1][2] = __builtin_amdgcn_mfma_f32_16x16x32_bf16(a1, b2, acc[1][2], 0, 0, 0);
            acc[1][3] = __builtin_amdgcn_mfma_f32_16x16x32_bf16(a1, b3, acc[1][3], 0, 0, 0);
            acc[2][0] = __builtin_amdgcn_mfma_f32_16x16x32_bf16(a2, b0, acc[2][0], 0, 0, 0);
            acc[2][1] = __builtin_amdgcn_mfma_f32_16x16x32_bf16(a2, b1, acc[2][1], 0, 0, 0);
            acc[2][2] = __builtin_amdgcn_mfma_f32_16x16x32_bf16(a2, b2, acc[2][2], 0, 0, 0);
            acc[2][3] = __builtin_amdgcn_mfma_f32_16x16x32_bf16(a2, b3, acc[2][3], 0, 0, 0);
            acc[3][0] = __builtin_amdgcn_mfma_f32_16x16x32_bf16(a3, b0, acc[3][0], 0, 0, 0);
            acc[3][1] = __builtin_amdgcn_mfma_f32_16x16x32_bf16(a3, b1, acc[3][1], 0, 0, 0);
            acc[3][2] = __builtin_amdgcn_mfma_f32_16x16x32_bf16(a3, b2, acc[3][2], 0, 0, 0);
            acc[3][3] = __builtin_amdgcn_mfma_f32_16x16x32_bf16(a3, b3, acc[3][3], 0, 0, 0);
            __builtin_amdgcn_s_setprio(0);

            // counted drain: tile tk+1 must be resident; tk+2's 4 loads stay in flight
            if (tk + 1 < NT) {
                if (tk + 2 < NT) WAIT_VM4();
                else             WAIT_VM0();
                BARRIER();
            }
            uint32_t tmp = o0; o0 = o1; o1 = o2; o2 = tmp;
        }

        // ---- epilogue: row = m0+wm*64+mi*16+g*4+q; col = n0+wn*64+nj*16+r16 ----
#pragma unroll
        for (int mi = 0; mi < 4; ++mi) {
#pragma unroll
            for (int nj = 0; nj < 4; ++nj) {
#pragma unroll
                for (int qq = 0; qq < 4; ++qq) {
                    int lr = wm * 64 + mi * 16 + g * 4 + qq;
                    if (m0 + lr < n_e) {
                        int col = n0 + wn * 64 + nj * 16 + r16;
                        float v = acc[mi][nj][qq];
                        if (SILU) {
                            v = v / (1.f + __expf(-v));
                            Hout[(size_t)(base + m0 + lr) * NW + col] = f2bf(v);
                        } else {
                            int tok = list[e * TOKENS + m0 + lr];
                            atomicAdd(&Yout[(size_t)tok * NW + col], v);
                        }
                    }
                }
            }
        }
    }
}

extern "C" void kernel_launch(void* const* d_in, const int* in_sizes, int n_in,
                              void* d_out, int out_size, void* d_ws, size_t ws_size,
                              hipStream_t stream) {
    const float* X  = (const float*)d_in[0];
    const float* Wr = (const float*)d_in[1];
    const float* W1 = (const float*)d_in[2];
    const float* W2 = (const float*)d_in[3];
    float* Y = (float*)d_out;

    char* ws = (char*)d_ws;
    int* cnt  = (int*)(ws + 0);
    int* off  = (int*)(ws + 64);
    int* wbA  = (int*)(ws + 128);
    int* wbB  = (int*)(ws + 192);
    int* qA   = (int*)(ws + 256);
    int* qlA  = (int*)(ws + 288);
    int* qB   = (int*)(ws + 320);
    int* qlB  = (int*)(ws + 352);
    int* list = (int*)(ws + 1024);                               // 128 KB
    unsigned short* Xb = (unsigned short*)(ws + (1ull << 20));   // 8 MB
    unsigned short* WT = (unsigned short*)(ws + (16ull << 20));  // 64 MB (W1T, then W2T)
    unsigned short* H  = (unsigned short*)(ws + (80ull << 20));  // 64 MB

    hipMemsetAsync(d_out, 0, (size_t)out_size * sizeof(float), stream);
    hipMemsetAsync(cnt, 0, 32, stream);

    cvt_x<<<TOKENS * DDIM / (256 * 8), 256, 0, stream>>>(X, Xb, TOKENS * DDIM);
    router<<<TOKENS / 4, 256, 0, stream>>>(X, Wr, cnt, list);
    setup<<<1, 64, 0, stream>>>(cnt, off, wbA, wbB, qA, qlA, qB, qlB);

    // W1 [E][D][F] -> W1T [E][F][D] bf16
    transpose_cvt<<<dim3(FDIM / 32, DDIM / 32, NEXP), 256, 0, stream>>>(W1, WT, DDIM, FDIM);
    // Pass A: H[slot][F] = silu(X[tok] @ W1[e]); K=1024
    gemm_moe9<true, true, 1><<<768, 256, 0, stream>>>(
        Xb, WT, cnt, off, list, wbA, qA, qlA, H, nullptr, DDIM, DDIM, FDIM);

    // W2 [E][F][D] -> W2T [E][D][F] bf16 (reuses WT)
    transpose_cvt<<<dim3(DDIM / 32, FDIM / 32, NEXP), 256, 0, stream>>>(W2, WT, FDIM, DDIM);
    // Pass B: Y[tok][D] += H[slot] @ W2[e]; K split 2 x 2048
    gemm_moe9<false, false, 2><<<768, 256, 0, stream>>>(
        H, WT, cnt, off, list, wbB, qB, qlB, nullptr, Y, FDIM, FDIM / 2, DDIM);
}

// Round 10
// 513.692 us; speedup vs baseline: 2.3883x; 2.3883x over previous
//
#include <hip/hip_runtime.h>
#include <hip/hip_bf16.h>
#include <stdint.h>

#define TOKENS 4096
#define DDIM 1024
#define FDIM 4096
#define NEXP 8
#define BM 256
#define BN 64
#define BK2 32

typedef __attribute__((ext_vector_type(4))) float f32x4;
typedef __attribute__((ext_vector_type(8))) short short8;

__device__ __forceinline__ unsigned short f2bf(float f) {
    union { float f; uint32_t u; } v; v.f = f;
    uint32_t u = v.u;
    return (unsigned short)((u + 0x7fff + ((u >> 16) & 1)) >> 16);
}

#define BARRIER() asm volatile("s_barrier" ::: "memory")
#define WAIT_VM0() asm volatile("s_waitcnt vmcnt(0)" ::: "memory")
#define WAIT_VM2() asm volatile("s_waitcnt vmcnt(2)" ::: "memory")
#define WAIT_VM3() asm volatile("s_waitcnt vmcnt(3)" ::: "memory")
#define WAIT_LGKM0() asm volatile("s_waitcnt lgkmcnt(0)" ::: "memory")
#define GLDS(SRC, DST) __builtin_amdgcn_global_load_lds( \
    (const __attribute__((address_space(1))) void*)(SRC), \
    (__attribute__((address_space(3))) void*)(DST), 16, 0, 0)

// opaque asm LDS read: explicit waits control all ordering (rule #18 applied at use)
__device__ __forceinline__ short8 dsr(uint32_t addr) {
    short8 d;
    asm volatile("ds_read_b128 %0, %1" : "=v"(d) : "v"(addr));
    return d;
}

// ---------------- X f32 -> bf16 ----------------
__global__ __launch_bounds__(256) void cvt_x(const float* __restrict__ x,
                                             unsigned short* __restrict__ xb, int n) {
    int i = (blockIdx.x * 256 + threadIdx.x) * 8;
    if (i >= n) return;
    float4 a = *(const float4*)(x + i);
    float4 b = *(const float4*)(x + i + 4);
    short8 o;
    o[0] = f2bf(a.x); o[1] = f2bf(a.y); o[2] = f2bf(a.z); o[3] = f2bf(a.w);
    o[4] = f2bf(b.x); o[5] = f2bf(b.y); o[6] = f2bf(b.z); o[7] = f2bf(b.w);
    *(short8*)(xb + i) = o;
}

// ------------- transpose + cvt: in [E][R][C] f32 -> out [E][C][R] bf16 -------------
__global__ __launch_bounds__(256) void transpose_cvt(const float* __restrict__ in,
                                                     unsigned short* __restrict__ out,
                                                     int R, int C) {
    __shared__ float tile[32][33];
    int e = blockIdx.z;
    int r0 = blockIdx.y * 32, c0 = blockIdx.x * 32;
    const float* src = in + (size_t)e * R * C;
    unsigned short* dst = out + (size_t)e * R * C;
    int t = threadIdx.x;
    int rr = t >> 3;
    int cc = (t & 7) * 4;
    float4 v = *(const float4*)(src + (size_t)(r0 + rr) * C + c0 + cc);
    tile[rr][cc + 0] = v.x; tile[rr][cc + 1] = v.y;
    tile[rr][cc + 2] = v.z; tile[rr][cc + 3] = v.w;
    __syncthreads();
    int oc = rr;
    int orr = cc;
    ushort4 o;
    o.x = f2bf(tile[orr + 0][oc]);
    o.y = f2bf(tile[orr + 1][oc]);
    o.z = f2bf(tile[orr + 2][oc]);
    o.w = f2bf(tile[orr + 3][oc]);
    *(ushort4*)(dst + (size_t)(c0 + oc) * R + r0 + orr) = o;
}

// ---------------- router: top-2 of 8 logits, build expert lists ----------------
__global__ __launch_bounds__(256) void router(const float* __restrict__ x,
                                              const float* __restrict__ wr,
                                              int* __restrict__ cnt,
                                              int* __restrict__ list) {
    __shared__ float wl[NEXP * DDIM];
    int t = threadIdx.x;
    for (int i = t; i < NEXP * DDIM; i += 256) wl[i] = wr[i];
    __syncthreads();
    int tok = blockIdx.x * 4 + (t >> 6);
    int lane = t & 63;
    float acc[NEXP];
#pragma unroll
    for (int e = 0; e < NEXP; e++) acc[e] = 0.f;
    const float* xr = x + (size_t)tok * DDIM;
    for (int d = lane; d < DDIM; d += 64) {
        float xv = xr[d];
#pragma unroll
        for (int e = 0; e < NEXP; e++) acc[e] += xv * wl[e * DDIM + d];
    }
#pragma unroll
    for (int e = 0; e < NEXP; e++) {
#pragma unroll
        for (int off = 32; off; off >>= 1) acc[e] += __shfl_xor(acc[e], off);
    }
    if (lane == 0) {
        int e1 = 0; float v1 = acc[0];
        for (int e = 1; e < NEXP; e++) if (acc[e] > v1) { v1 = acc[e]; e1 = e; }
        int e2 = -1; float v2 = -1e30f;
        for (int e = 0; e < NEXP; e++) if (e != e1 && acc[e] > v2) { v2 = acc[e]; e2 = e; }
        int p1 = atomicAdd(&cnt[e1], 1);
        list[e1 * TOKENS + p1] = tok;
        int p2 = atomicAdd(&cnt[e2], 1);
        list[e2 * TOKENS + p2] = tok;
    }
}

// ---------------- setup: offsets, work bases (BM=256 tiles), queue reset ----------------
// items per expert = ntm * 64 for BOTH passes (A: 64 n-tiles of 64; B: 16 n-tiles x 4 k-chunks)
__global__ void setup(const int* __restrict__ cnt, int* __restrict__ off,
                      int* __restrict__ wbA, int* __restrict__ wbB,
                      int* __restrict__ qctr) {
    if (threadIdx.x == 0) {
        int s = 0, ta = 0, tb = 0;
        for (int e = 0; e < NEXP; e++) {
            off[e] = s; s += cnt[e];
            wbA[e] = ta; wbB[e] = tb;
            int ntm = (cnt[e] + BM - 1) >> 8;
            ta += ntm * 64;
            tb += ntm * 64;
        }
        wbA[NEXP] = ta; wbB[NEXP] = tb;
        qctr[0] = 0; qctr[1] = 0;
    }
}

// ---- persistent grouped GEMM: BM=256 x BN=64, BK=32, 3-slot ring, 512 thr, 2 blk/CU ----
// Round-8 loop skeleton verbatim; geometry change only: taller M-tile amortizes B panels.
// Waves 0-3 stage A(2)+B(1) chunks -> vmcnt(3); waves 4-7 stage A(2) -> vmcnt(2).
template <bool GATHER_A, bool SILU, int KSPLIT>
__global__ __launch_bounds__(512, 2) void gemm_moe10(
    const unsigned short* __restrict__ Abase,
    const unsigned short* __restrict__ Wt,      // [E][NW][KD] bf16
    const int* __restrict__ cnt, const int* __restrict__ off,
    const int* __restrict__ list,
    const int* __restrict__ wbase,
    int* __restrict__ qctr,
    unsigned short* __restrict__ Hout,          // SILU out, stride NW
    float* __restrict__ Yout,                   // atomic out, stride NW
    int KD, int KLEN, int NW) {
    __shared__ alignas(16) unsigned short As[3][BM * BK2];  // 3 x 16 KB
    __shared__ alignas(16) unsigned short Bs[3][BN * BK2];  // 3 x 4 KB
    __shared__ int wsh;

    const int t = threadIdx.x;
    const int lane = t & 63;
    const int wid = t >> 6;
    const int wm = wid >> 1, wn = wid & 1;     // 4M x 2N
    const int r16 = lane & 15, g = lane >> 4;
    const bool loadsB = (wid < 4);
    const int total = wbase[NEXP];

    // frag addresses within slot 0; chunk g stored at g^((row>>1)&3)
    const uint32_t asB = (uint32_t)(uintptr_t)&As[0][0];
    const uint32_t bsB = (uint32_t)(uintptr_t)&Bs[0][0];
    uint32_t aAdr[4], bAdr[2];
#pragma unroll
    for (int mi = 0; mi < 4; mi++) {
        int row = wm * 64 + mi * 16 + r16;                 // 0..255
        aAdr[mi] = asB + row * 64 + ((g ^ ((row >> 1) & 3)) << 4);
    }
#pragma unroll
    for (int nj = 0; nj < 2; nj++) {
        int row = wn * 32 + nj * 16 + r16;                 // 0..63
        bAdr[nj] = bsB + row * 64 + ((g ^ ((row >> 1) & 3)) << 4);
    }

    for (;;) {
        if (t == 0) wsh = atomicAdd(qctr, 1);
        __syncthreads();
        int w = wsh;
        if (w >= total) break;

        // ---- decode: expert e; (n-tile, k-chunk) outer, m-tile inner ----
        int e = 0;
        while (e < NEXP - 1 && w >= wbase[e + 1]) e++;
        w -= wbase[e];
        const int n_e = cnt[e];
        const int ntm = (n_e + BM - 1) >> 8;
        int combined = w / ntm;
        const int mtile = w - combined * ntm;
        const int kc = combined & (KSPLIT - 1);
        const int idx = combined / KSPLIT;
        const int m0 = mtile * BM;
        const int n0 = idx * BN;
        const int base = off[e];
        const int k0 = kc * KLEN;

        // ---- staging pointers: A 2 chunks/thread (all); B 1 chunk/thread (t<256) ----
        const unsigned short* pA[2];
        int ldsA[2];
#pragma unroll
        for (int i = 0; i < 2; i++) {
            int c = i * 512 + t;
            int row = c >> 2, p = c & 3;
            int cg = p ^ ((row >> 1) & 3);
            int arow = m0 + row; if (arow >= n_e) arow = n_e - 1;
            size_t grow = GATHER_A ? (size_t)list[e * TOKENS + arow] : (size_t)(base + arow);
            pA[i] = Abase + grow * (size_t)KD + k0 + (cg << 3);
            ldsA[i] = c * 16;
        }
        const unsigned short* pB;
        int ldsB;
        {
            int c = t & 255;
            int row = c >> 2, p = c & 3;
            int cg = p ^ ((row >> 1) & 3);
            pB = Wt + ((size_t)e * NW + n0 + row) * (size_t)KD + k0 + (cg << 3);
            ldsB = c * 16;
        }

        f32x4 acc[4][2];
#pragma unroll
        for (int i = 0; i < 4; i++)
#pragma unroll
            for (int j = 0; j < 2; j++) acc[i][j] = f32x4{0.f, 0.f, 0.f, 0.f};

        // ---- prologue: stage tiles 0,1 into slots 0,1 ----
#pragma unroll
        for (int s = 0; s < 2; ++s) {
#pragma unroll
            for (int i = 0; i < 2; i++) { GLDS(pA[i], (char*)As[s] + ldsA[i]); pA[i] += BK2; }
            if (loadsB) { GLDS(pB, (char*)Bs[s] + ldsB); pB += BK2; }
        }
        if (loadsB) WAIT_VM3(); else WAIT_VM2();
        BARRIER();

        // ring-slot byte offsets: compute (uA0,uB0), ready (..1), stage (..2)
        uint32_t uA0 = 0, uA1 = 16384, uA2 = 32768;
        uint32_t uB0 = 0, uB1 = 4096, uB2 = 8192;

        const int NT = KLEN / BK2;
        for (int tk = 0; tk < NT; ++tk) {
            // issue stage for tile tk+2 into the slot freed at last barrier
            if (tk + 2 < NT) {
#pragma unroll
                for (int i = 0; i < 2; i++) { GLDS(pA[i], (char*)As[0] + uA2 + ldsA[i]); pA[i] += BK2; }
                if (loadsB) { GLDS(pB, (char*)Bs[0] + uB2 + ldsB); pB += BK2; }
            }

            // fragment loads: opaque asm ds_read_b128 from compute slot
            short8 a0 = dsr(aAdr[0] + uA0);
            short8 a1 = dsr(aAdr[1] + uA0);
            short8 a2 = dsr(aAdr[2] + uA0);
            short8 a3 = dsr(aAdr[3] + uA0);
            short8 b0 = dsr(bAdr[0] + uB0);
            short8 b1 = dsr(bAdr[1] + uB0);
            WAIT_LGKM0();
            __builtin_amdgcn_sched_barrier(0);   // rule #18

            __builtin_amdgcn_s_setprio(1);
            acc[0][0] = __builtin_amdgcn_mfma_f32_16x16x32_bf16(a0, b0, acc[0][0], 0, 0, 0);
            acc[0][1] = __builtin_amdgcn_mfma_f32_16x16x32_bf16(a0, b1, acc[0][1], 0, 0, 0);
            acc[1][0] = __builtin_amdgcn_mfma_f32_16x16x32_bf16(a1, b0, acc[1][0], 0, 0, 0);
            acc[1][1] = __builtin_amdgcn_mfma_f32_16x16x32_bf16(a1, b1, acc[1][1], 0, 0, 0);
            acc[2][0] = __builtin_amdgcn_mfma_f32_16x16x32_bf16(a2, b0, acc[2][0], 0, 0, 0);
            acc[2][1] = __builtin_amdgcn_mfma_f32_16x16x32_bf16(a2, b1, acc[2][1], 0, 0, 0);
            acc[3][0] = __builtin_amdgcn_mfma_f32_16x16x32_bf16(a3, b0, acc[3][0], 0, 0, 0);
            acc[3][1] = __builtin_amdgcn_mfma_f32_16x16x32_bf16(a3, b1, acc[3][1], 0, 0, 0);
            __builtin_amdgcn_s_setprio(0);

            // counted drain: tile tk+1 resident; tk+2's loads stay in flight
            if (tk + 1 < NT) {
                if (tk + 2 < NT) { if (loadsB) WAIT_VM3(); else WAIT_VM2(); }
                else             WAIT_VM0();
                BARRIER();
            }
            uint32_t ta_ = uA0; uA0 = uA1; uA1 = uA2; uA2 = ta_;
            uint32_t tb_ = uB0; uB0 = uB1; uB1 = uB2; uB2 = tb_;
        }

        // ---- epilogue: row = m0+wm*64+mi*16+g*4+q; col = n0+wn*32+nj*16+r16 ----
#pragma unroll
        for (int mi = 0; mi < 4; ++mi) {
#pragma unroll
            for (int nj = 0; nj < 2; ++nj) {
#pragma unroll
                for (int qq = 0; qq < 4; ++qq) {
                    int lr = wm * 64 + mi * 16 + g * 4 + qq;
                    if (m0 + lr < n_e) {
                        int col = n0 + wn * 32 + nj * 16 + r16;
                        float v = acc[mi][nj][qq];
                        if (SILU) {
                            v = v / (1.f + __expf(-v));
                            Hout[(size_t)(base + m0 + lr) * NW + col] = f2bf(v);
                        } else {
                            int tok = list[e * TOKENS + m0 + lr];
                            atomicAdd(&Yout[(size_t)tok * NW + col], v);
                        }
                    }
                }
            }
        }
    }
}

extern "C" void kernel_launch(void* const* d_in, const int* in_sizes, int n_in,
                              void* d_out, int out_size, void* d_ws, size_t ws_size,
                              hipStream_t stream) {
    const float* X  = (const float*)d_in[0];
    const float* Wr = (const float*)d_in[1];
    const float* W1 = (const float*)d_in[2];
    const float* W2 = (const float*)d_in[3];
    float* Y = (float*)d_out;

    char* ws = (char*)d_ws;
    int* cnt  = (int*)(ws + 0);
    int* off  = (int*)(ws + 64);
    int* wbA  = (int*)(ws + 128);
    int* wbB  = (int*)(ws + 192);
    int* qctr = (int*)(ws + 256);
    int* list = (int*)(ws + 1024);                               // 128 KB
    unsigned short* Xb = (unsigned short*)(ws + (1ull << 20));   // 8 MB
    unsigned short* WT = (unsigned short*)(ws + (16ull << 20));  // 64 MB (W1T, then W2T)
    unsigned short* H  = (unsigned short*)(ws + (80ull << 20));  // 64 MB

    hipMemsetAsync(d_out, 0, (size_t)out_size * sizeof(float), stream);
    hipMemsetAsync(cnt, 0, 32, stream);

    cvt_x<<<TOKENS * DDIM / (256 * 8), 256, 0, stream>>>(X, Xb, TOKENS * DDIM);
    router<<<TOKENS / 4, 256, 0, stream>>>(X, Wr, cnt, list);
    setup<<<1, 64, 0, stream>>>(cnt, off, wbA, wbB, qctr);

    // W1 [E][D][F] -> W1T [E][F][D] bf16
    transpose_cvt<<<dim3(FDIM / 32, DDIM / 32, NEXP), 256, 0, stream>>>(W1, WT, DDIM, FDIM);
    // Pass A: H[slot][F] = silu(X[tok] @ W1[e]); K=1024, 64 n-tiles of 64
    gemm_moe10<true, true, 1><<<512, 512, 0, stream>>>(
        Xb, WT, cnt, off, list, wbA, qctr + 0, H, nullptr, DDIM, DDIM, FDIM);

    // W2 [E][F][D] -> W2T [E][D][F] bf16 (reuses WT)
    transpose_cvt<<<dim3(DDIM / 32, FDIM / 32, NEXP), 256, 0, stream>>>(W2, WT, FDIM, DDIM);
    // Pass B: Y[tok][D] += H[slot] @ W2[e]; 16 n-tiles x 4 k-chunks of 1024
    gemm_moe10<false, false, 4><<<512, 512, 0, stream>>>(
        H, WT, cnt, off, list, wbB, qctr + 1, nullptr, Y, FDIM, FDIM / 4, DDIM);
}

// Round 11
// 498.332 us; speedup vs baseline: 2.4619x; 1.0308x over previous
//
#include <hip/hip_runtime.h>
#include <hip/hip_bf16.h>
#include <stdint.h>

#define TOKENS 4096
#define DDIM 1024
#define FDIM 4096
#define NEXP 8
#define BM 256
#define BN 128
#define BK2 32

typedef __attribute__((ext_vector_type(4))) float f32x4;
typedef __attribute__((ext_vector_type(8))) short short8;

__device__ __forceinline__ unsigned short f2bf(float f) {
    union { float f; uint32_t u; } v; v.f = f;
    uint32_t u = v.u;
    return (unsigned short)((u + 0x7fff + ((u >> 16) & 1)) >> 16);
}

#define BARRIER() asm volatile("s_barrier" ::: "memory")
#define WAIT_VM0() asm volatile("s_waitcnt vmcnt(0)" ::: "memory")
#define WAIT_VM3() asm volatile("s_waitcnt vmcnt(3)" ::: "memory")
#define WAIT_LGKM0() asm volatile("s_waitcnt lgkmcnt(0)" ::: "memory")
#define GLDS(SRC, DST) __builtin_amdgcn_global_load_lds( \
    (const __attribute__((address_space(1))) void*)(SRC), \
    (__attribute__((address_space(3))) void*)(DST), 16, 0, 0)

// opaque asm LDS read: explicit waits control all ordering (rule #18 applied at use)
__device__ __forceinline__ short8 dsr(uint32_t addr) {
    short8 d;
    asm volatile("ds_read_b128 %0, %1" : "=v"(d) : "v"(addr));
    return d;
}

// ---------------- X f32 -> bf16 ----------------
__global__ __launch_bounds__(256) void cvt_x(const float* __restrict__ x,
                                             unsigned short* __restrict__ xb, int n) {
    int i = (blockIdx.x * 256 + threadIdx.x) * 8;
    if (i >= n) return;
    float4 a = *(const float4*)(x + i);
    float4 b = *(const float4*)(x + i + 4);
    short8 o;
    o[0] = f2bf(a.x); o[1] = f2bf(a.y); o[2] = f2bf(a.z); o[3] = f2bf(a.w);
    o[4] = f2bf(b.x); o[5] = f2bf(b.y); o[6] = f2bf(b.z); o[7] = f2bf(b.w);
    *(short8*)(xb + i) = o;
}

// ------------- transpose + cvt: in [E][R][C] f32 -> out [E][C][R] bf16 -------------
__global__ __launch_bounds__(256) void transpose_cvt(const float* __restrict__ in,
                                                     unsigned short* __restrict__ out,
                                                     int R, int C) {
    __shared__ float tile[32][33];
    int e = blockIdx.z;
    int r0 = blockIdx.y * 32, c0 = blockIdx.x * 32;
    const float* src = in + (size_t)e * R * C;
    unsigned short* dst = out + (size_t)e * R * C;
    int t = threadIdx.x;
    int rr = t >> 3;
    int cc = (t & 7) * 4;
    float4 v = *(const float4*)(src + (size_t)(r0 + rr) * C + c0 + cc);
    tile[rr][cc + 0] = v.x; tile[rr][cc + 1] = v.y;
    tile[rr][cc + 2] = v.z; tile[rr][cc + 3] = v.w;
    __syncthreads();
    int oc = rr;
    int orr = cc;
    ushort4 o;
    o.x = f2bf(tile[orr + 0][oc]);
    o.y = f2bf(tile[orr + 1][oc]);
    o.z = f2bf(tile[orr + 2][oc]);
    o.w = f2bf(tile[orr + 3][oc]);
    *(ushort4*)(dst + (size_t)(c0 + oc) * R + r0 + orr) = o;
}

// ---------------- router: top-2 of 8 logits, build expert lists ----------------
__global__ __launch_bounds__(256) void router(const float* __restrict__ x,
                                              const float* __restrict__ wr,
                                              int* __restrict__ cnt,
                                              int* __restrict__ list) {
    __shared__ float wl[NEXP * DDIM];
    int t = threadIdx.x;
    for (int i = t; i < NEXP * DDIM; i += 256) wl[i] = wr[i];
    __syncthreads();
    int tok = blockIdx.x * 4 + (t >> 6);
    int lane = t & 63;
    float acc[NEXP];
#pragma unroll
    for (int e = 0; e < NEXP; e++) acc[e] = 0.f;
    const float* xr = x + (size_t)tok * DDIM;
    for (int d = lane; d < DDIM; d += 64) {
        float xv = xr[d];
#pragma unroll
        for (int e = 0; e < NEXP; e++) acc[e] += xv * wl[e * DDIM + d];
    }
#pragma unroll
    for (int e = 0; e < NEXP; e++) {
#pragma unroll
        for (int off = 32; off; off >>= 1) acc[e] += __shfl_xor(acc[e], off);
    }
    if (lane == 0) {
        int e1 = 0; float v1 = acc[0];
        for (int e = 1; e < NEXP; e++) if (acc[e] > v1) { v1 = acc[e]; e1 = e; }
        int e2 = -1; float v2 = -1e30f;
        for (int e = 0; e < NEXP; e++) if (e != e1 && acc[e] > v2) { v2 = acc[e]; e2 = e; }
        int p1 = atomicAdd(&cnt[e1], 1);
        list[e1 * TOKENS + p1] = tok;
        int p2 = atomicAdd(&cnt[e2], 1);
        list[e2 * TOKENS + p2] = tok;
    }
}

// ---------------- setup: offsets, work bases (BM=256), queue reset ----------------
__global__ void setup(const int* __restrict__ cnt, int* __restrict__ off,
                      int* __restrict__ wbA, int* __restrict__ wbB,
                      int* __restrict__ qctr) {
    if (threadIdx.x == 0) {
        int s = 0, ta = 0, tb = 0;
        for (int e = 0; e < NEXP; e++) {
            off[e] = s; s += cnt[e];
            wbA[e] = ta; wbB[e] = tb;
            int ntm = (cnt[e] + BM - 1) >> 8;
            ta += ntm * (FDIM / BN);        // pass A: 32 n-tiles of 128
            tb += ntm * (DDIM / BN) * 2;    // pass B: 8 n-tiles x 2 k-chunks
        }
        wbA[NEXP] = ta; wbB[NEXP] = tb;
        qctr[0] = 0; qctr[1] = 0;
    }
}

// ---- persistent grouped GEMM: BM=256 x BN=128, BK=32, 3-slot ring, 512 thr, 2 blk/CU ----
// Round-8 loop skeleton verbatim: stage-first GLDS -> asm ds_read -> lgkm0 -> sched_barrier
// -> MFMA -> counted vmcnt -> s_barrier. 3 GLDS/thread/tile (2 A + 1 B) -> steady vmcnt(3).
template <bool GATHER_A, bool SILU, int KSPLIT>
__global__ __launch_bounds__(512, 2) void gemm_moe11(
    const unsigned short* __restrict__ Abase,
    const unsigned short* __restrict__ Wt,      // [E][NW][KD] bf16
    const int* __restrict__ cnt, const int* __restrict__ off,
    const int* __restrict__ list,
    const int* __restrict__ wbase,
    int* __restrict__ qctr,
    unsigned short* __restrict__ Hout,          // SILU out, stride NW
    float* __restrict__ Yout,                   // atomic out, stride NW
    int KD, int KLEN, int NW) {
    __shared__ alignas(16) unsigned short As[3][BM * BK2];  // 3 x 16 KB
    __shared__ alignas(16) unsigned short Bs[3][BN * BK2];  // 3 x 8 KB
    __shared__ int wsh;

    const int t = threadIdx.x;
    const int lane = t & 63;
    const int wid = t >> 6;
    const int wm = wid >> 1, wn = wid & 1;     // 4M x 2N waves
    const int r16 = lane & 15, g = lane >> 4;
    const int total = wbase[NEXP];

    // frag addresses within slot 0; chunk g stored at g^((row>>1)&3) (both-sides swizzle)
    const uint32_t asB = (uint32_t)(uintptr_t)&As[0][0];
    const uint32_t bsB = (uint32_t)(uintptr_t)&Bs[0][0];
    uint32_t aAdr[4], bAdr[4];
#pragma unroll
    for (int mi = 0; mi < 4; mi++) {
        int row = wm * 64 + mi * 16 + r16;                 // 0..255
        aAdr[mi] = asB + row * 64 + ((g ^ ((row >> 1) & 3)) << 4);
    }
#pragma unroll
    for (int nj = 0; nj < 4; nj++) {
        int row = wn * 64 + nj * 16 + r16;                 // 0..127
        bAdr[nj] = bsB + row * 64 + ((g ^ ((row >> 1) & 3)) << 4);
    }

    for (;;) {
        if (t == 0) wsh = atomicAdd(qctr, 1);
        __syncthreads();
        int w = wsh;
        if (w >= total) break;

        // ---- decode: expert e; (n-tile [, k-chunk]) outer, m-tile inner ----
        int e = 0;
        while (e < NEXP - 1 && w >= wbase[e + 1]) e++;
        w -= wbase[e];
        const int n_e = cnt[e];
        const int ntm = (n_e + BM - 1) >> 8;
        int combined = w / ntm;
        const int mtile = w - combined * ntm;
        const int kc = (KSPLIT == 2) ? (combined & 1) : 0;
        const int idx = (KSPLIT == 2) ? (combined >> 1) : combined;
        const int m0 = mtile * BM;
        const int n0 = idx * BN;
        const int base = off[e];
        const int k0 = kc * KLEN;

        // ---- staging pointers: A 2 chunks/thread; B 1 chunk/thread ----
        const unsigned short* pA[2];
        int ldsA[2];
#pragma unroll
        for (int i = 0; i < 2; i++) {
            int c = i * 512 + t;                 // 0..1023
            int row = c >> 2, p = c & 3;         // row 0..255
            int cg = p ^ ((row >> 1) & 3);
            int arow = m0 + row; if (arow >= n_e) arow = n_e - 1;
            size_t grow = GATHER_A ? (size_t)list[e * TOKENS + arow] : (size_t)(base + arow);
            pA[i] = Abase + grow * (size_t)KD + k0 + (cg << 3);
            ldsA[i] = c * 16;
        }
        const unsigned short* pB;
        int ldsB;
        {
            int c = t;                           // 0..511
            int row = c >> 2, p = c & 3;         // row 0..127
            int cg = p ^ ((row >> 1) & 3);
            pB = Wt + ((size_t)e * NW + n0 + row) * (size_t)KD + k0 + (cg << 3);
            ldsB = c * 16;
        }

        f32x4 acc[4][4];
#pragma unroll
        for (int i = 0; i < 4; i++)
#pragma unroll
            for (int j = 0; j < 4; j++) acc[i][j] = f32x4{0.f, 0.f, 0.f, 0.f};

        // ---- prologue: stage tiles 0,1 into slots 0,1 (6 GLDS/thread) ----
#pragma unroll
        for (int s = 0; s < 2; ++s) {
#pragma unroll
            for (int i = 0; i < 2; i++) { GLDS(pA[i], (char*)As[s] + ldsA[i]); pA[i] += BK2; }
            GLDS(pB, (char*)Bs[s] + ldsB); pB += BK2;
        }
        WAIT_VM3();   // tile 0 resident; tile 1 still in flight
        BARRIER();

        // ring-slot byte offsets: compute (uA0,uB0), ready (..1), stage (..2)
        uint32_t uA0 = 0, uA1 = 16384, uA2 = 32768;
        uint32_t uB0 = 0, uB1 = 8192, uB2 = 16384;

        const int NT = KLEN / BK2;
        for (int tk = 0; tk < NT; ++tk) {
            // issue stage for tile tk+2 into the slot freed at last barrier
            if (tk + 2 < NT) {
#pragma unroll
                for (int i = 0; i < 2; i++) { GLDS(pA[i], (char*)As[0] + uA2 + ldsA[i]); pA[i] += BK2; }
                GLDS(pB, (char*)Bs[0] + uB2 + ldsB); pB += BK2;
            }

            // fragment loads: opaque asm ds_read_b128 from compute slot
            short8 a0 = dsr(aAdr[0] + uA0);
            short8 a1 = dsr(aAdr[1] + uA0);
            short8 a2 = dsr(aAdr[2] + uA0);
            short8 a3 = dsr(aAdr[3] + uA0);
            short8 b0 = dsr(bAdr[0] + uB0);
            short8 b1 = dsr(bAdr[1] + uB0);
            short8 b2 = dsr(bAdr[2] + uB0);
            short8 b3 = dsr(bAdr[3] + uB0);
            WAIT_LGKM0();
            __builtin_amdgcn_sched_barrier(0);   // rule #18

            __builtin_amdgcn_s_setprio(1);
            acc[0][0] = __builtin_amdgcn_mfma_f32_16x16x32_bf16(a0, b0, acc[0][0], 0, 0, 0);
            acc[0][1] = __builtin_amdgcn_mfma_f32_16x16x32_bf16(a0, b1, acc[0][1], 0, 0, 0);
            acc[0][2] = __builtin_amdgcn_mfma_f32_16x16x32_bf16(a0, b2, acc[0][2], 0, 0, 0);
            acc[0][3] = __builtin_amdgcn_mfma_f32_16x16x32_bf16(a0, b3, acc[0][3], 0, 0, 0);
            acc[1][0] = __builtin_amdgcn_mfma_f32_16x16x32_bf16(a1, b0, acc[1][0], 0, 0, 0);
            acc[1][1] = __builtin_amdgcn_mfma_f32_16x16x32_bf16(a1, b1, acc[1][1], 0, 0, 0);
            acc[1][2] = __builtin_amdgcn_mfma_f32_16x16x32_bf16(a1, b2, acc[1][2], 0, 0, 0);
            acc[1][3] = __builtin_amdgcn_mfma_f32_16x16x32_bf16(a1, b3, acc[1][3], 0, 0, 0);
            acc[2][0] = __builtin_amdgcn_mfma_f32_16x16x32_bf16(a2, b0, acc[2][0], 0, 0, 0);
            acc[2][1] = __builtin_amdgcn_mfma_f32_16x16x32_bf16(a2, b1, acc[2][1], 0, 0, 0);
            acc[2][2] = __builtin_amdgcn_mfma_f32_16x16x32_bf16(a2, b2, acc[2][2], 0, 0, 0);
            acc[2][3] = __builtin_amdgcn_mfma_f32_16x16x32_bf16(a2, b3, acc[2][3], 0, 0, 0);
            acc[3][0] = __builtin_amdgcn_mfma_f32_16x16x32_bf16(a3, b0, acc[3][0], 0, 0, 0);
            acc[3][1] = __builtin_amdgcn_mfma_f32_16x16x32_bf16(a3, b1, acc[3][1], 0, 0, 0);
            acc[3][2] = __builtin_amdgcn_mfma_f32_16x16x32_bf16(a3, b2, acc[3][2], 0, 0, 0);
            acc[3][3] = __builtin_amdgcn_mfma_f32_16x16x32_bf16(a3, b3, acc[3][3], 0, 0, 0);
            __builtin_amdgcn_s_setprio(0);

            // counted drain: tile tk+1 resident; tk+2's 3 loads stay in flight
            if (tk + 1 < NT) {
                if (tk + 2 < NT) WAIT_VM3();
                else             WAIT_VM0();
                BARRIER();
            }
            uint32_t ta_ = uA0; uA0 = uA1; uA1 = uA2; uA2 = ta_;
            uint32_t tb_ = uB0; uB0 = uB1; uB1 = uB2; uB2 = tb_;
        }

        // ---- epilogue: row = m0+wm*64+mi*16+g*4+q; col = n0+wn*64+nj*16+r16 ----
#pragma unroll
        for (int mi = 0; mi < 4; ++mi) {
#pragma unroll
            for (int nj = 0; nj < 4; ++nj) {
#pragma unroll
                for (int qq = 0; qq < 4; ++qq) {
                    int lr = wm * 64 + mi * 16 + g * 4 + qq;
                    if (m0 + lr < n_e) {
                        int col = n0 + wn * 64 + nj * 16 + r16;
                        float v = acc[mi][nj][qq];
                        if (SILU) {
                            v = v / (1.f + __expf(-v));
                            Hout[(size_t)(base + m0 + lr) * NW + col] = f2bf(v);
                        } else {
                            int tok = list[e * TOKENS + m0 + lr];
                            atomicAdd(&Yout[(size_t)tok * NW + col], v);
                        }
                    }
                }
            }
        }
    }
}

extern "C" void kernel_launch(void* const* d_in, const int* in_sizes, int n_in,
                              void* d_out, int out_size, void* d_ws, size_t ws_size,
                              hipStream_t stream) {
    const float* X  = (const float*)d_in[0];
    const float* Wr = (const float*)d_in[1];
    const float* W1 = (const float*)d_in[2];
    const float* W2 = (const float*)d_in[3];
    float* Y = (float*)d_out;

    char* ws = (char*)d_ws;
    int* cnt  = (int*)(ws + 0);
    int* off  = (int*)(ws + 64);
    int* wbA  = (int*)(ws + 128);
    int* wbB  = (int*)(ws + 192);
    int* qctr = (int*)(ws + 256);
    int* list = (int*)(ws + 1024);                               // 128 KB
    unsigned short* Xb = (unsigned short*)(ws + (1ull << 20));   // 8 MB
    unsigned short* WT = (unsigned short*)(ws + (16ull << 20));  // 64 MB (W1T, then W2T)
    unsigned short* H  = (unsigned short*)(ws + (80ull << 20));  // 64 MB

    hipMemsetAsync(d_out, 0, (size_t)out_size * sizeof(float), stream);
    hipMemsetAsync(cnt, 0, 32, stream);

    cvt_x<<<TOKENS * DDIM / (256 * 8), 256, 0, stream>>>(X, Xb, TOKENS * DDIM);
    router<<<TOKENS / 4, 256, 0, stream>>>(X, Wr, cnt, list);
    setup<<<1, 64, 0, stream>>>(cnt, off, wbA, wbB, qctr);

    // W1 [E][D][F] -> W1T [E][F][D] bf16
    transpose_cvt<<<dim3(FDIM / 32, DDIM / 32, NEXP), 256, 0, stream>>>(W1, WT, DDIM, FDIM);
    // Pass A: H[slot][F] = silu(X[tok] @ W1[e]); K=1024, 32 n-tiles of 128
    gemm_moe11<true, true, 1><<<512, 512, 0, stream>>>(
        Xb, WT, cnt, off, list, wbA, qctr + 0, H, nullptr, DDIM, DDIM, FDIM);

    // W2 [E][F][D] -> W2T [E][D][F] bf16 (reuses WT)
    transpose_cvt<<<dim3(DDIM / 32, FDIM / 32, NEXP), 256, 0, stream>>>(W2, WT, FDIM, DDIM);
    // Pass B: Y[tok][D] += H[slot] @ W2[e]; 8 n-tiles x 2 k-chunks of 2048
    gemm_moe11<false, false, 2><<<512, 512, 0, stream>>>(
        H, WT, cnt, off, list, wbB, qctr + 1, nullptr, Y, FDIM, FDIM / 2, DDIM);
}